// Round 8
// baseline (598.299 us; speedup 1.0000x reference)
//
#include <hip/hip_runtime.h>

#define N_NODES 100000
#define N_EDGES 1200000
#define D 64
#define KEEP_PROB 0.7f
#define INV_KEEP (1.0f / KEEP_PROB)
#define NBUCK 782          // ceil(N_NODES / 128) row-range buckets
#define MAXB 1800          // LDS record capacity (mean ~1536, +6.7 sigma)

#define ALOAD_I(p)   __hip_atomic_load((p), __ATOMIC_RELAXED, __HIP_MEMORY_SCOPE_AGENT)
#define ALOAD_U64(p) __hip_atomic_load((p), __ATOMIC_RELAXED, __HIP_MEMORY_SCOPE_AGENT)

// ---------------------------------------------------------------------------
__global__ __launch_bounds__(256) void zero_kernel(float4* __restrict__ p, int n4) {
    int i = blockIdx.x * 256 + threadIdx.x;
    if (i < n4) p[i] = make_float4(0.f, 0.f, 0.f, 0.f);
}
__global__ __launch_bounds__(256) void zero_ints_kernel(int* __restrict__ p, int n) {
    int i = blockIdx.x * 256 + threadIdx.x;
    if (i < n) p[i] = 0;
}

// ---------------------------------------------------------------------------
// Build 1: per-bucket edge counts (bucket = row >> 7)
__global__ __launch_bounds__(256) void bucket_hist_kernel(const int4* __restrict__ rows4,
                                                          int* __restrict__ bcnt) {
    int i = blockIdx.x * 256 + threadIdx.x;
    if (i >= N_EDGES / 4) return;
    int4 r = rows4[i];
    atomicAdd(&bcnt[r.x >> 7], 1);
    atomicAdd(&bcnt[r.y >> 7], 1);
    atomicAdd(&bcnt[r.z >> 7], 1);
    atomicAdd(&bcnt[r.w >> 7], 1);
}

// ---------------------------------------------------------------------------
// Build 2: single-block exclusive scan of 782 bucket counts -> bbase (+sentinel),
// init bucket cursors (64B-strided to spread atomic slices), Pstart sentinel.
__global__ __launch_bounds__(256) void bucket_scan_kernel(const int* __restrict__ bcnt,
                                                          int* __restrict__ bbase,
                                                          int* __restrict__ bcur,
                                                          int* __restrict__ Pstart) {
    __shared__ int part[256];
    int t = threadIdx.x;
    int e[4]; int s = 0;
    #pragma unroll
    for (int k = 0; k < 4; ++k) {
        int j = t * 4 + k;
        e[k] = (j < NBUCK) ? ALOAD_I(&bcnt[j]) : 0;
        s += e[k];
    }
    part[t] = s;
    __syncthreads();
    for (int d = 1; d < 256; d <<= 1) {
        int w = (t >= d) ? part[t - d] : 0;
        __syncthreads();
        part[t] += w;
        __syncthreads();
    }
    int run = part[t] - s;
    #pragma unroll
    for (int k = 0; k < 4; ++k) {
        int j = t * 4 + k;
        if (j < NBUCK) { bbase[j] = run; bcur[j << 4] = run; run += e[k]; }
    }
    if (t == 255) bbase[NBUCK] = run;            // == N_EDGES
    if (t == 0)   Pstart[N_NODES] = N_EDGES;     // global sentinel
}

// ---------------------------------------------------------------------------
// Build 3: partition edges into buckets (append => line-local writes in time).
// Record: (col, v0, v1, row). Dropout pre-folded.
__global__ __launch_bounds__(256) void partition_kernel(
    const int4*   __restrict__ rows4,
    const int4*   __restrict__ cols4,
    const float4* __restrict__ vals4,
    const float4* __restrict__ u04,
    const float4* __restrict__ u14,
    int*          __restrict__ bcur,
    uint4*        __restrict__ edata) {
    int i = blockIdx.x * 256 + threadIdx.x;
    if (i >= N_EDGES / 4) return;
    int4   r  = rows4[i];
    int4   c  = cols4[i];
    float4 v  = vals4[i];
    float4 u0 = u04[i];
    float4 u1 = u14[i];

    int p0 = atomicAdd(&bcur[(r.x >> 7) << 4], 1);
    int p1 = atomicAdd(&bcur[(r.y >> 7) << 4], 1);
    int p2 = atomicAdd(&bcur[(r.z >> 7) << 4], 1);
    int p3 = atomicAdd(&bcur[(r.w >> 7) << 4], 1);

    uint4 rec; float vv;
    vv = v.x * INV_KEEP;
    rec.x = (unsigned)c.x;
    rec.y = __float_as_uint((u0.x + KEEP_PROB >= 1.0f) ? vv : 0.f);
    rec.z = __float_as_uint((u1.x + KEEP_PROB >= 1.0f) ? vv : 0.f);
    rec.w = (unsigned)r.x;
    edata[p0] = rec;
    vv = v.y * INV_KEEP;
    rec.x = (unsigned)c.y;
    rec.y = __float_as_uint((u0.y + KEEP_PROB >= 1.0f) ? vv : 0.f);
    rec.z = __float_as_uint((u1.y + KEEP_PROB >= 1.0f) ? vv : 0.f);
    rec.w = (unsigned)r.y;
    edata[p1] = rec;
    vv = v.z * INV_KEEP;
    rec.x = (unsigned)c.z;
    rec.y = __float_as_uint((u0.z + KEEP_PROB >= 1.0f) ? vv : 0.f);
    rec.z = __float_as_uint((u1.z + KEEP_PROB >= 1.0f) ? vv : 0.f);
    rec.w = (unsigned)r.z;
    edata[p2] = rec;
    vv = v.w * INV_KEEP;
    rec.x = (unsigned)c.w;
    rec.y = __float_as_uint((u0.w + KEEP_PROB >= 1.0f) ? vv : 0.f);
    rec.z = __float_as_uint((u1.w + KEEP_PROB >= 1.0f) ? vv : 0.f);
    rec.w = (unsigned)r.w;
    edata[p3] = rec;
}

// ---------------------------------------------------------------------------
// Build 4: one block per bucket. Load bucket records to LDS, count/scan the
// 128 rows locally, write Pstart, place final (col,v0,col,v1) records
// IN-PLACE over the bucket's region (one-CU L2 locality).
// Overflow (>MAXB, ~never: 6.7 sigma) spills via the x1 scratch region.
__global__ __launch_bounds__(256) void finalize_kernel(
    uint4* __restrict__ edata,          // in/out (tmp records -> final records)
    const int* __restrict__ bbase,
    int*   __restrict__ Pstart,
    uint4* __restrict__ scratch) {      // x1 region (unwritten at this point)
    __shared__ uint4 recs[MAXB];
    __shared__ int cnt[128], cur[128], part[128];
    int b = blockIdx.x;
    int t = threadIdx.x;
    int base = bbase[b];
    int size = bbase[b + 1] - base;
    int row0 = b << 7;
    bool small = (size <= MAXB);

    const unsigned long long* src = (const unsigned long long*)(edata + base);
    if (small) {
        for (int i = t; i < size; i += 256) {
            unsigned long long lo = ALOAD_U64(src + 2 * i);
            unsigned long long hi = ALOAD_U64(src + 2 * i + 1);
            uint4 r;
            r.x = (unsigned)lo; r.y = (unsigned)(lo >> 32);
            r.z = (unsigned)hi; r.w = (unsigned)(hi >> 32);
            recs[i] = r;
        }
    } else {
        unsigned long long* dst = (unsigned long long*)(scratch + base);
        for (int i = t; i < 2 * size; i += 256) dst[i] = ALOAD_U64(src + i);
    }
    if (t < 128) cnt[t] = 0;
    __syncthreads();

    const uint4* gsrc = scratch + base;
    for (int i = t; i < size; i += 256) {
        unsigned rw = small ? recs[i].w : gsrc[i].w;
        atomicAdd(&cnt[rw & 127], 1);
    }
    __syncthreads();

    int v = (t < 128) ? cnt[t] : 0;
    if (t < 128) part[t] = v;
    __syncthreads();
    for (int d = 1; d < 128; d <<= 1) {
        int w = (t >= d && t < 128) ? part[t - d] : 0;
        __syncthreads();
        if (t < 128) part[t] += w;
        __syncthreads();
    }
    int R = N_NODES - row0; if (R > 128) R = 128;
    if (t < 128) {
        int pref = part[t] - v;      // exclusive prefix within bucket
        cur[t] = pref;
        if (t < R) Pstart[row0 + t] = base + pref;
    }
    __syncthreads();

    for (int i = t; i < size; i += 256) {
        uint4 r = small ? recs[i] : gsrc[i];
        int lr = (int)(r.w & 127);
        int slot = atomicAdd(&cur[lr], 1);
        uint4 outrec;
        outrec.x = r.x; outrec.y = r.y;     // (col, v0,
        outrec.z = r.x; outrec.w = r.z;     //  col, v1)
        edata[base + slot] = outrec;
    }
}

// ---------------------------------------------------------------------------
// Gather SpMM (unchanged from R7): 16 lanes/row, 4 rows/wave, unroll 8,
// dropped edges remapped to hot row 0 (branch-free).
__global__ __launch_bounds__(256) void spmm_gather_kernel(
    const float4* __restrict__ x_in,
    const unsigned long long* __restrict__ edata,  // 2 u64 per edge
    const int*   __restrict__ Pstart,
    float4*      __restrict__ io,
    int layer) {
    int tid = blockIdx.x * 256 + threadIdx.x;
    int row = tid >> 4;
    int l16 = threadIdx.x & 15;
    if (row >= N_NODES) return;
    int start = ALOAD_I(&Pstart[row]);
    int end   = ALOAD_I(&Pstart[row + 1]);
    float4 acc = make_float4(0.f, 0.f, 0.f, 0.f);
    #pragma unroll 8
    for (int i = start; i < end; ++i) {
        unsigned long long rec = ALOAD_U64(&edata[2 * i + layer]);
        int   c = (int)(rec & 0xffffffffu);
        float v = __uint_as_float((unsigned)(rec >> 32));
        int  cc = (v != 0.f) ? c : 0;
        float4 x = x_in[(cc << 4) + l16];
        acc.x = fmaf(v, x.x, acc.x);
        acc.y = fmaf(v, x.y, acc.y);
        acc.z = fmaf(v, x.z, acc.z);
        acc.w = fmaf(v, x.w, acc.w);
    }
    int o = (row << 4) + l16;
    if (layer == 0) {
        io[o] = acc;
    } else {
        float4 p = io[o];
        p.x = (p.x + acc.x) * (1.0f / 3.0f);
        p.y = (p.y + acc.y) * (1.0f / 3.0f);
        p.z = (p.z + acc.z) * (1.0f / 3.0f);
        p.w = (p.w + acc.w) * (1.0f / 3.0f);
        io[o] = p;
    }
}

// ---------------------------------------------------------------------------
// out[n,j] = b[j] + sum_k emb[n,k]*W[j,k] + x1[n,j]
__global__ __launch_bounds__(256) void fc_add_kernel(
    const float* __restrict__ emb,
    const float* __restrict__ W,
    const float* __restrict__ b,
    const float* __restrict__ x1,
    float*       __restrict__ out) {
    __shared__ float Ws[D * 65];
    __shared__ float Es[4 * D];

    int t = threadIdx.x;
    #pragma unroll
    for (int i = 0; i < 16; ++i) {
        int idx = i * 256 + t;
        Ws[(idx >> 6) * 65 + (idx & 63)] = W[idx];
    }
    int node0 = blockIdx.x * 4;
    Es[t] = emb[node0 * D + t];
    __syncthreads();

    int local = t >> 6;
    int j     = t & 63;
    int n     = node0 + local;

    float acc = b[j];
    const float* es = &Es[local * D];
    const float* ws = &Ws[j * 65];
    #pragma unroll
    for (int k = 0; k < D; ++k) acc += es[k] * ws[k];
    out[n * D + j] = acc + x1[n * D + j];
}

// ---------------------------------------------------------------------------
// Fallback (atomic path, replay-proven) if ws too small
__global__ __launch_bounds__(256) void spmm_atomic_kernel(
    const float* __restrict__ x_in,
    const float* __restrict__ vals,
    const float* __restrict__ drop_u,
    const int*   __restrict__ rows,
    const int*   __restrict__ cols,
    float*       __restrict__ x_out) {
    int wave = (blockIdx.x * 256 + threadIdx.x) >> 6;
    int lane = threadIdx.x & 63;
    if (wave >= N_EDGES) return;
    float u = drop_u[wave];
    if (u + KEEP_PROB < 1.0f) return;
    float v = vals[wave] * INV_KEEP;
    atomicAdd(&x_out[rows[wave] * D + lane], v * x_in[cols[wave] * D + lane]);
}

__global__ __launch_bounds__(256) void scale_kernel(float4* __restrict__ p, int n4) {
    int i = blockIdx.x * 256 + threadIdx.x;
    if (i < n4) {
        float4 v = p[i];
        v.x *= (1.f/3.f); v.y *= (1.f/3.f); v.z *= (1.f/3.f); v.w *= (1.f/3.f);
        p[i] = v;
    }
}

// ---------------------------------------------------------------------------
extern "C" void kernel_launch(void* const* d_in, const int* in_sizes, int n_in,
                              void* d_out, int out_size, void* d_ws, size_t ws_size,
                              hipStream_t stream) {
    const float* all_emb = (const float*)d_in[0];
    const float* W       = (const float*)d_in[1];
    const float* b       = (const float*)d_in[2];
    const float* vals    = (const float*)d_in[3];
    const float* drop_u  = (const float*)d_in[4];   // [2, E]
    const int*   rows    = (const int*)d_in[5];
    const int*   cols    = (const int*)d_in[6];

    float* out = (float*)d_out;

    // workspace layout (16B/64B aligned)
    char* ws = (char*)d_ws;
    float* x1     = (float*)(ws);                   // 25,600,000 B (also overflow scratch)
    int*   Pstart = (int*)  (ws + 25600000);        //    400,064 B (N+1 ints)
    uint4* edata  = (uint4*)(ws + 26000064);        // 19,200,000 B (E x 16B, in-place)
    int*   bcnt   = (int*)  (ws + 45200064);        //      3,200 B
    int*   bbase  = (int*)  (ws + 45203264);        //      3,200 B (NBUCK+1)
    int*   bcur   = (int*)  (ws + 45206464);        //     50,048 B (64B-strided)
    const size_t WS_NEEDED = 45256512;

    const int n4 = N_NODES * D / 4;
    const int zb = (n4 + 255) / 256;
    const int e4_blocks = (N_EDGES / 4 + 255) / 256;      // 1172
    const int gather_blocks = (N_NODES * 16 + 255) / 256; // 6250

    if (ws_size >= WS_NEEDED) {
        zero_ints_kernel<<<(NBUCK + 255) / 256, 256, 0, stream>>>(bcnt, NBUCK);
        bucket_hist_kernel<<<e4_blocks, 256, 0, stream>>>((const int4*)rows, bcnt);
        bucket_scan_kernel<<<1, 256, 0, stream>>>(bcnt, bbase, bcur, Pstart);
        partition_kernel<<<e4_blocks, 256, 0, stream>>>(
            (const int4*)rows, (const int4*)cols, (const float4*)vals,
            (const float4*)drop_u, (const float4*)(drop_u + N_EDGES),
            bcur, edata);
        finalize_kernel<<<NBUCK, 256, 0, stream>>>(edata, bbase, Pstart, (uint4*)x1);
        // layer 0: x1 = A1 @ all_emb
        spmm_gather_kernel<<<gather_blocks, 256, 0, stream>>>(
            (const float4*)all_emb, (const unsigned long long*)edata, Pstart,
            (float4*)x1, 0);
        // out = fc(all_emb) + x1
        fc_add_kernel<<<N_NODES / 4, 256, 0, stream>>>(all_emb, W, b, x1, out);
        // layer 1 (fused /3): out = (out + A2 @ x1) / 3
        spmm_gather_kernel<<<gather_blocks, 256, 0, stream>>>(
            (const float4*)x1, (const unsigned long long*)edata, Pstart,
            (float4*)out, 1);
    } else {
        // fallback: proven atomic path
        const int spmm_blocks = (N_EDGES + 3) / 4;
        zero_kernel<<<zb, 256, 0, stream>>>((float4*)x1, n4);
        spmm_atomic_kernel<<<spmm_blocks, 256, 0, stream>>>(all_emb, vals, drop_u,
                                                            rows, cols, x1);
        fc_add_kernel<<<N_NODES / 4, 256, 0, stream>>>(all_emb, W, b, x1, out);
        spmm_atomic_kernel<<<spmm_blocks, 256, 0, stream>>>(x1, vals,
                                                            drop_u + N_EDGES,
                                                            rows, cols, out);
        scale_kernel<<<zb, 256, 0, stream>>>((float4*)out, n4);
    }
}

// Round 9
// 334.674 us; speedup vs baseline: 1.7877x; 1.7877x over previous
//
#include <hip/hip_runtime.h>

#define N_NODES 100000
#define N_EDGES 1200000
#define D 64
#define KEEP_PROB 0.7f
#define INV_KEEP (1.0f / KEEP_PROB)
#define NBUCK 1564         // ceil(N_NODES / 64) row-range buckets (row >> 6)
#define MAXB 1024          // LDS record capacity (mean ~767, +9.3 sigma)
#define HIST_BLOCKS 256

#define ALOAD_I(p)   __hip_atomic_load((p), __ATOMIC_RELAXED, __HIP_MEMORY_SCOPE_AGENT)
#define ALOAD_U64(p) __hip_atomic_load((p), __ATOMIC_RELAXED, __HIP_MEMORY_SCOPE_AGENT)

// ---------------------------------------------------------------------------
__global__ __launch_bounds__(256) void zero_kernel(float4* __restrict__ p, int n4) {
    int i = blockIdx.x * 256 + threadIdx.x;
    if (i < n4) p[i] = make_float4(0.f, 0.f, 0.f, 0.f);
}
__global__ __launch_bounds__(256) void zero_ints_kernel(int* __restrict__ p, int n) {
    int i = blockIdx.x * 256 + threadIdx.x;
    if (i < n) p[i] = 0;
}

// ---------------------------------------------------------------------------
// Build 1: per-bucket counts via per-block LDS histogram (contention fix:
// global atomics reduced 1.2M -> ~NBUCK per block, onto 64B-strided counters).
__global__ __launch_bounds__(256) void bucket_hist_kernel(const int4* __restrict__ rows4,
                                                          int* __restrict__ bcnt) {
    __shared__ int h[NBUCK];
    int t = threadIdx.x;
    for (int i = t; i < NBUCK; i += 256) h[i] = 0;
    __syncthreads();
    const int total = N_EDGES / 4;
    for (int i = blockIdx.x * 256 + t; i < total; i += HIST_BLOCKS * 256) {
        int4 r = rows4[i];
        atomicAdd(&h[r.x >> 6], 1);
        atomicAdd(&h[r.y >> 6], 1);
        atomicAdd(&h[r.z >> 6], 1);
        atomicAdd(&h[r.w >> 6], 1);
    }
    __syncthreads();
    for (int i = t; i < NBUCK; i += 256) {
        int c = h[i];
        if (c) atomicAdd(&bcnt[i << 4], c);   // 64B-strided counters
    }
}

// ---------------------------------------------------------------------------
// Build 2: single-block exclusive scan of NBUCK strided counts -> bbase,
// init strided bucket cursors, sentinels.
__global__ __launch_bounds__(256) void bucket_scan_kernel(const int* __restrict__ bcnt,
                                                          int* __restrict__ bbase,
                                                          int* __restrict__ bcur,
                                                          int* __restrict__ Pstart) {
    __shared__ int part[256];
    const int CH = 7;   // 256*7 = 1792 >= NBUCK
    int t = threadIdx.x;
    int e[CH]; int s = 0;
    #pragma unroll
    for (int k = 0; k < CH; ++k) {
        int j = t * CH + k;
        e[k] = (j < NBUCK) ? ALOAD_I(&bcnt[j << 4]) : 0;
        s += e[k];
    }
    part[t] = s;
    __syncthreads();
    for (int d = 1; d < 256; d <<= 1) {
        int w = (t >= d) ? part[t - d] : 0;
        __syncthreads();
        part[t] += w;
        __syncthreads();
    }
    int run = part[t] - s;
    #pragma unroll
    for (int k = 0; k < CH; ++k) {
        int j = t * CH + k;
        if (j < NBUCK) { bbase[j] = run; bcur[j << 4] = run; run += e[k]; }
    }
    if (t == 255) bbase[NBUCK] = run;            // == N_EDGES
    if (t == 0)   Pstart[N_NODES] = N_EDGES;     // global sentinel
}

// ---------------------------------------------------------------------------
// Build 3: partition edges into buckets (appends = line-local in time).
// Record: (col, v0, v1, row). Dropout pre-folded.
__global__ __launch_bounds__(256) void partition_kernel(
    const int4*   __restrict__ rows4,
    const int4*   __restrict__ cols4,
    const float4* __restrict__ vals4,
    const float4* __restrict__ u04,
    const float4* __restrict__ u14,
    int*          __restrict__ bcur,
    uint4*        __restrict__ edata) {
    int i = blockIdx.x * 256 + threadIdx.x;
    if (i >= N_EDGES / 4) return;
    int4   r  = rows4[i];
    int4   c  = cols4[i];
    float4 v  = vals4[i];
    float4 u0 = u04[i];
    float4 u1 = u14[i];

    int p0 = atomicAdd(&bcur[(r.x >> 6) << 4], 1);
    int p1 = atomicAdd(&bcur[(r.y >> 6) << 4], 1);
    int p2 = atomicAdd(&bcur[(r.z >> 6) << 4], 1);
    int p3 = atomicAdd(&bcur[(r.w >> 6) << 4], 1);

    uint4 rec; float vv;
    vv = v.x * INV_KEEP;
    rec.x = (unsigned)c.x;
    rec.y = __float_as_uint((u0.x + KEEP_PROB >= 1.0f) ? vv : 0.f);
    rec.z = __float_as_uint((u1.x + KEEP_PROB >= 1.0f) ? vv : 0.f);
    rec.w = (unsigned)r.x;
    edata[p0] = rec;
    vv = v.y * INV_KEEP;
    rec.x = (unsigned)c.y;
    rec.y = __float_as_uint((u0.y + KEEP_PROB >= 1.0f) ? vv : 0.f);
    rec.z = __float_as_uint((u1.y + KEEP_PROB >= 1.0f) ? vv : 0.f);
    rec.w = (unsigned)r.y;
    edata[p1] = rec;
    vv = v.z * INV_KEEP;
    rec.x = (unsigned)c.z;
    rec.y = __float_as_uint((u0.z + KEEP_PROB >= 1.0f) ? vv : 0.f);
    rec.z = __float_as_uint((u1.z + KEEP_PROB >= 1.0f) ? vv : 0.f);
    rec.w = (unsigned)r.z;
    edata[p2] = rec;
    vv = v.w * INV_KEEP;
    rec.x = (unsigned)c.w;
    rec.y = __float_as_uint((u0.w + KEEP_PROB >= 1.0f) ? vv : 0.f);
    rec.z = __float_as_uint((u1.w + KEEP_PROB >= 1.0f) ? vv : 0.f);
    rec.w = (unsigned)r.w;
    edata[p3] = rec;
}

// ---------------------------------------------------------------------------
// Build 4: one block per bucket (64 rows). LDS-sort records by row, write
// Pstart + final (col,v0,col,v1) records in-place. Overflow spills via scratch.
__global__ __launch_bounds__(256) void finalize_kernel(
    uint4* __restrict__ edata,
    const int* __restrict__ bbase,
    int*   __restrict__ Pstart,
    uint4* __restrict__ scratch) {      // x1 region (unwritten at this point)
    __shared__ uint4 recs[MAXB];
    __shared__ int cnt[64], cur[64], part[64];
    int b = blockIdx.x;
    int t = threadIdx.x;
    int base = bbase[b];
    int size = bbase[b + 1] - base;
    int row0 = b << 6;
    bool small = (size <= MAXB);

    const unsigned long long* src = (const unsigned long long*)(edata + base);
    if (small) {
        for (int i = t; i < size; i += 256) {
            unsigned long long lo = ALOAD_U64(src + 2 * i);
            unsigned long long hi = ALOAD_U64(src + 2 * i + 1);
            uint4 r;
            r.x = (unsigned)lo; r.y = (unsigned)(lo >> 32);
            r.z = (unsigned)hi; r.w = (unsigned)(hi >> 32);
            recs[i] = r;
        }
    } else {
        unsigned long long* dst = (unsigned long long*)(scratch + base);
        for (int i = t; i < 2 * size; i += 256) dst[i] = ALOAD_U64(src + i);
    }
    if (t < 64) cnt[t] = 0;
    __syncthreads();

    const uint4* gsrc = scratch + base;
    for (int i = t; i < size; i += 256) {
        unsigned rw = small ? recs[i].w : gsrc[i].w;
        atomicAdd(&cnt[rw & 63], 1);
    }
    __syncthreads();

    int v = (t < 64) ? cnt[t] : 0;
    if (t < 64) part[t] = v;
    __syncthreads();
    for (int d = 1; d < 64; d <<= 1) {
        int w = (t >= d && t < 64) ? part[t - d] : 0;
        __syncthreads();
        if (t < 64) part[t] += w;
        __syncthreads();
    }
    int R = N_NODES - row0; if (R > 64) R = 64;
    if (t < 64) {
        int pref = part[t] - v;
        cur[t] = pref;
        if (t < R) Pstart[row0 + t] = base + pref;
    }
    __syncthreads();

    for (int i = t; i < size; i += 256) {
        uint4 r = small ? recs[i] : gsrc[i];
        int lr = (int)(r.w & 63);
        int slot = atomicAdd(&cur[lr], 1);
        uint4 outrec;
        outrec.x = r.x; outrec.y = r.y;     // (col, v0,
        outrec.z = r.x; outrec.w = r.z;     //  col, v1)
        edata[base + slot] = outrec;
    }
}

// ---------------------------------------------------------------------------
// Gather SpMM (R7-proven): 16 lanes/row, 4 rows/wave, unroll 8,
// dropped edges remapped to hot row 0 (branch-free).
__global__ __launch_bounds__(256) void spmm_gather_kernel(
    const float4* __restrict__ x_in,
    const unsigned long long* __restrict__ edata,
    const int*   __restrict__ Pstart,
    float4*      __restrict__ io,
    int layer) {
    int tid = blockIdx.x * 256 + threadIdx.x;
    int row = tid >> 4;
    int l16 = threadIdx.x & 15;
    if (row >= N_NODES) return;
    int start = ALOAD_I(&Pstart[row]);
    int end   = ALOAD_I(&Pstart[row + 1]);
    float4 acc = make_float4(0.f, 0.f, 0.f, 0.f);
    #pragma unroll 8
    for (int i = start; i < end; ++i) {
        unsigned long long rec = ALOAD_U64(&edata[2 * i + layer]);
        int   c = (int)(rec & 0xffffffffu);
        float v = __uint_as_float((unsigned)(rec >> 32));
        int  cc = (v != 0.f) ? c : 0;
        float4 x = x_in[(cc << 4) + l16];
        acc.x = fmaf(v, x.x, acc.x);
        acc.y = fmaf(v, x.y, acc.y);
        acc.z = fmaf(v, x.z, acc.z);
        acc.w = fmaf(v, x.w, acc.w);
    }
    int o = (row << 4) + l16;
    if (layer == 0) {
        io[o] = acc;
    } else {
        float4 p = io[o];
        p.x = (p.x + acc.x) * (1.0f / 3.0f);
        p.y = (p.y + acc.y) * (1.0f / 3.0f);
        p.z = (p.z + acc.z) * (1.0f / 3.0f);
        p.w = (p.w + acc.w) * (1.0f / 3.0f);
        io[o] = p;
    }
}

// ---------------------------------------------------------------------------
// out[n,j] = b[j] + sum_k emb[n,k]*W[j,k] + x1[n,j]
__global__ __launch_bounds__(256) void fc_add_kernel(
    const float* __restrict__ emb,
    const float* __restrict__ W,
    const float* __restrict__ b,
    const float* __restrict__ x1,
    float*       __restrict__ out) {
    __shared__ float Ws[D * 65];
    __shared__ float Es[4 * D];

    int t = threadIdx.x;
    #pragma unroll
    for (int i = 0; i < 16; ++i) {
        int idx = i * 256 + t;
        Ws[(idx >> 6) * 65 + (idx & 63)] = W[idx];
    }
    int node0 = blockIdx.x * 4;
    Es[t] = emb[node0 * D + t];
    __syncthreads();

    int local = t >> 6;
    int j     = t & 63;
    int n     = node0 + local;

    float acc = b[j];
    const float* es = &Es[local * D];
    const float* ws = &Ws[j * 65];
    #pragma unroll
    for (int k = 0; k < D; ++k) acc += es[k] * ws[k];
    out[n * D + j] = acc + x1[n * D + j];
}

// ---------------------------------------------------------------------------
// Fallback (atomic path, replay-proven) if ws too small
__global__ __launch_bounds__(256) void spmm_atomic_kernel(
    const float* __restrict__ x_in,
    const float* __restrict__ vals,
    const float* __restrict__ drop_u,
    const int*   __restrict__ rows,
    const int*   __restrict__ cols,
    float*       __restrict__ x_out) {
    int wave = (blockIdx.x * 256 + threadIdx.x) >> 6;
    int lane = threadIdx.x & 63;
    if (wave >= N_EDGES) return;
    float u = drop_u[wave];
    if (u + KEEP_PROB < 1.0f) return;
    float v = vals[wave] * INV_KEEP;
    atomicAdd(&x_out[rows[wave] * D + lane], v * x_in[cols[wave] * D + lane]);
}

__global__ __launch_bounds__(256) void scale_kernel(float4* __restrict__ p, int n4) {
    int i = blockIdx.x * 256 + threadIdx.x;
    if (i < n4) {
        float4 v = p[i];
        v.x *= (1.f/3.f); v.y *= (1.f/3.f); v.z *= (1.f/3.f); v.w *= (1.f/3.f);
        p[i] = v;
    }
}

// ---------------------------------------------------------------------------
extern "C" void kernel_launch(void* const* d_in, const int* in_sizes, int n_in,
                              void* d_out, int out_size, void* d_ws, size_t ws_size,
                              hipStream_t stream) {
    const float* all_emb = (const float*)d_in[0];
    const float* W       = (const float*)d_in[1];
    const float* b       = (const float*)d_in[2];
    const float* vals    = (const float*)d_in[3];
    const float* drop_u  = (const float*)d_in[4];   // [2, E]
    const int*   rows    = (const int*)d_in[5];
    const int*   cols    = (const int*)d_in[6];

    float* out = (float*)d_out;

    // workspace layout
    char* ws = (char*)d_ws;
    float* x1     = (float*)(ws);                   // 25,600,000 B (+ overflow scratch)
    int*   Pstart = (int*)  (ws + 25600000);        //    400,064 B
    uint4* edata  = (uint4*)(ws + 26000064);        // 19,200,000 B
    int*   bcnt   = (int*)  (ws + 45200064);        //    100,096 B (NBUCK x 64B)
    int*   bbase  = (int*)  (ws + 45300160);        //      6,272 B (NBUCK+1)
    int*   bcur   = (int*)  (ws + 45306432);        //    100,096 B (NBUCK x 64B)
    const size_t WS_NEEDED = 45406528;

    const int n4 = N_NODES * D / 4;
    const int zb = (n4 + 255) / 256;
    const int e4_blocks = (N_EDGES / 4 + 255) / 256;      // 1172
    const int gather_blocks = (N_NODES * 16 + 255) / 256; // 6250

    if (ws_size >= WS_NEEDED) {
        zero_ints_kernel<<<(NBUCK * 16 + 255) / 256, 256, 0, stream>>>(bcnt, NBUCK * 16);
        bucket_hist_kernel<<<HIST_BLOCKS, 256, 0, stream>>>((const int4*)rows, bcnt);
        bucket_scan_kernel<<<1, 256, 0, stream>>>(bcnt, bbase, bcur, Pstart);
        partition_kernel<<<e4_blocks, 256, 0, stream>>>(
            (const int4*)rows, (const int4*)cols, (const float4*)vals,
            (const float4*)drop_u, (const float4*)(drop_u + N_EDGES),
            bcur, edata);
        finalize_kernel<<<NBUCK, 256, 0, stream>>>(edata, bbase, Pstart, (uint4*)x1);
        // layer 0: x1 = A1 @ all_emb
        spmm_gather_kernel<<<gather_blocks, 256, 0, stream>>>(
            (const float4*)all_emb, (const unsigned long long*)edata, Pstart,
            (float4*)x1, 0);
        // out = fc(all_emb) + x1
        fc_add_kernel<<<N_NODES / 4, 256, 0, stream>>>(all_emb, W, b, x1, out);
        // layer 1 (fused /3): out = (out + A2 @ x1) / 3
        spmm_gather_kernel<<<gather_blocks, 256, 0, stream>>>(
            (const float4*)x1, (const unsigned long long*)edata, Pstart,
            (float4*)out, 1);
    } else {
        // fallback: proven atomic path
        const int spmm_blocks = (N_EDGES + 3) / 4;
        zero_kernel<<<zb, 256, 0, stream>>>((float4*)x1, n4);
        spmm_atomic_kernel<<<spmm_blocks, 256, 0, stream>>>(all_emb, vals, drop_u,
                                                            rows, cols, x1);
        fc_add_kernel<<<N_NODES / 4, 256, 0, stream>>>(all_emb, W, b, x1, out);
        spmm_atomic_kernel<<<spmm_blocks, 256, 0, stream>>>(x1, vals,
                                                            drop_u + N_EDGES,
                                                            rows, cols, out);
        scale_kernel<<<zb, 256, 0, stream>>>((float4*)out, n4);
    }
}